// Round 6
// baseline (228.219 us; speedup 1.0000x reference)
//
#include <hip/hip_runtime.h>
#include <cstdint>
#include <cstddef>

typedef unsigned short u16;
typedef __bf16 bf16x8 __attribute__((ext_vector_type(8)));
typedef float floatx4 __attribute__((ext_vector_type(4)));

#define NPTS 4096
#define MGRD 4096
#define DDIM 8

#define AS1 __attribute__((address_space(1)))
#define AS3 __attribute__((address_space(3)))

// round-to-nearest-even fp32 -> bf16
static __device__ __forceinline__ u16 f2bf(float f) {
    uint32_t u = __float_as_uint(f);
    u += 0x7fffu + ((u >> 16) & 1u);
    return (u16)(u >> 16);
}

// ---------------- Fused prep ----------------
// blocks 0..511:      kstar (verified, unchanged)
// blocks 512..4607:   tril transpose; skip condition relaxed to 256-wide m-tiles
//                     (by < (bx & ~3)) -- the 256^2 gemm needs k >= 256*(bx>>2).
// blocks 4608..5631:  zero C[:, 0:2048) -- the split-K atomicAdd region.
__global__ __launch_bounds__(256) void prep_kernel(
    const float* __restrict__ x, const float* __restrict__ g,
    const float* __restrict__ ls, const float* __restrict__ B,
    u16* __restrict__ A, u16* __restrict__ Bt, float* __restrict__ C)
{
    __shared__ float tile[64][65];
    const int bid = blockIdx.x;
    const int tid = threadIdx.x;

    if (bid < 512) {
        // ---- kstar ----
        const int kb = bid & 1;
        const int n0 = (bid >> 1) * 16;
        const int k0 = kb * 2048 + tid * 8;

        float il[DDIM];
#pragma unroll
        for (int d = 0; d < DDIM; ++d) il[d] = 1.0f / ls[d];

        float4 g0[8], g1[8];
#pragma unroll
        for (int r = 0; r < 8; ++r) {
            g0[r] = *reinterpret_cast<const float4*>(g + (size_t)(k0 + r) * DDIM);
            g1[r] = *reinterpret_cast<const float4*>(g + (size_t)(k0 + r) * DDIM + 4);
        }

        for (int nn = 0; nn < 16; ++nn) {
            const int n = n0 + nn;
            const float4 x0 = *reinterpret_cast<const float4*>(x + (size_t)n * DDIM);
            const float4 x1 = *reinterpret_cast<const float4*>(x + (size_t)n * DDIM + 4);
            alignas(16) u16 res[8];
#pragma unroll
            for (int r = 0; r < 8; ++r) {
                float s = fabsf(x0.x - g0[r].x) * il[0] + fabsf(x0.y - g0[r].y) * il[1]
                        + fabsf(x0.z - g0[r].z) * il[2] + fabsf(x0.w - g0[r].w) * il[3]
                        + fabsf(x1.x - g1[r].x) * il[4] + fabsf(x1.y - g1[r].y) * il[5]
                        + fabsf(x1.z - g1[r].z) * il[6] + fabsf(x1.w - g1[r].w) * il[7];
                res[r] = f2bf(__expf(-s));
            }
            *reinterpret_cast<uint4*>(A + (size_t)n * MGRD + k0) =
                *reinterpret_cast<const uint4*>(res);
        }
    } else if (bid < 4608) {
        // ---- transpose + convert (tiles needed by 256-wide-m triangular GEMM) ----
        const int id = bid - 512;
        const int bx = id & 63;          // m-tile (64 rows of Bt)
        const int by = id >> 6;          // k-tile
        if (by < (bx & ~3)) return;      // gemm needs k >= 256*(bx>>2) = 64*(bx&~3)
        const int k0 = by * 64;
        const int m0 = bx * 64;

#pragma unroll
        for (int r = 0; r < 4; ++r) {
            int c   = r * 256 + tid;
            int row = c >> 4;
            int col = (c & 15) * 4;
            const float4 v = *reinterpret_cast<const float4*>(&B[(size_t)(k0 + row) * MGRD + m0 + col]);
            tile[row][col + 0] = v.x; tile[row][col + 1] = v.y;
            tile[row][col + 2] = v.z; tile[row][col + 3] = v.w;
        }
        __syncthreads();

#pragma unroll
        for (int r = 0; r < 2; ++r) {
            int c  = r * 256 + tid;
            int mr = c >> 3;
            int kc = (c & 7) * 8;
            alignas(16) u16 tmp[8];
#pragma unroll
            for (int j = 0; j < 8; ++j)
                tmp[j] = f2bf(tile[kc + j][mr]);
            *reinterpret_cast<uint4*>(&Bt[(size_t)(m0 + mr) * MGRD + k0 + kc]) =
                *reinterpret_cast<const uint4*>(tmp);
        }
    } else {
        // ---- zero split-K atomic region C[:, 0:2048) ----
        const int z   = bid - 4608;          // 0..1023
        const int row = z * 4 + (tid >> 6);  // 0..4095
        float4* cp = reinterpret_cast<float4*>(C + (size_t)row * MGRD);
        const int cb = tid & 63;
#pragma unroll
        for (int v = 0; v < 8; ++v)
            cp[cb + v * 64] = make_float4(0.f, 0.f, 0.f, 0.f);
    }
}

// ---------------- R11: m201-faithful 256^2 8-phase triangular GEMM ----------------
// R5-R10 established: at 256x128-class tiles every schedule sums the pipes
// (~2700 cyc/K64 = LDS 1152 + MFMA 1241 + writes 384); the learn-loop regime
// gate (m230b/m232) says overlap only materializes at the exact 256^2 8-phase
// geometry (m201: 3299 cyc per 256^2-K64 vs 5299 sum = 38% overlap, 1563 TF).
// This is that template, ported verbatim:
//   BM=BN=256, BK=64, 512 thr / 8 waves (2M x 4N), per-wave 128x64 out
//   (acc[8][4]), LDS 2 buffers x (A 256x64 + B 256x64) = 128 KB.
//   Per K-tile, 4 phases: P1 reads A-frags0-3+B0-1, MFMA quad(0,0);
//   P2 reads B2-3, quad(0,1); P3 reads A4-7, quad(1,0); P4 quad(1,1).
//   Stage slots (2 gload_lds each): P1: a1a3[T+1] (buf^1), P2: a0a2[T+2],
//   P3: b0b1[T+2], P4: b2b3[T+2] (all into the CURRENT buf -- each granule
//   staged one phase after its last read, barrier-separated). One vmcnt(6)
//   per K-tile at P4 (keeps exactly P2-P4's 6 issues in flight; confirms
//   tile T+1 completely). Load flight >= 6 phases >> HBM latency.
// Triangular balance (exact): jobs (bn, bm) with L = 64-4bm K-tiles. Jobs
// bm<=7 split at k=2048 into seg-H (32) + seg-L (32-4bm). Per bn, 16 slots:
// slots 0-7 = seg-H(bm=slot) [32 units]; slots 8-15 = pairs
// (seg-L bm=p, whole bm=15-p) [32-4p + 4+4p = 36 units]. 256 blocks, 1/CU,
// makespan 36 units. Split tiles (m<2048): zero-init in prep + HW fp32
// unsafeAtomicAdd epilogue (2 order-free writers); bm>=8: plain stores.
// Staging map, XOR swizzle, read addressing, C/D layout identical to the
// R2-verified patterns. Rule-18: sched_barrier(0) after every lgkmcnt asm.

#define FENCE() asm volatile("" ::: "memory")
static __device__ __forceinline__ void bar() {
    FENCE(); __builtin_amdgcn_s_barrier(); FENCE();
}
#define LGKM0() do { asm volatile("s_waitcnt lgkmcnt(0)" ::: "memory");          \
                     __builtin_amdgcn_sched_barrier(0); } while (0)
#define VMCNT6() asm volatile("s_waitcnt vmcnt(6)" ::: "memory")
#define VMCNT0() asm volatile("s_waitcnt vmcnt(0)" ::: "memory")

__global__ __launch_bounds__(512, 2) void gemm_8ph_kernel(
    const u16* __restrict__ A,    // [4096][4096] bf16 (n-major, k contiguous)
    const u16* __restrict__ Bt,   // [4096][4096] bf16 (m-major, k contiguous)
    float* __restrict__ C)        // [4096][4096] fp32
{
    // 2 buffers x (A 256x64 (32KB) + B 256x64 (32KB)) = 128 KB
    __shared__ u16 lds[2 * 32768] __attribute__((aligned(16)));

    const int tid  = threadIdx.x;
    const int lane = tid & 63;
    const int w    = tid >> 6;          // 0..7
    const int wm   = (w >> 2) * 128;    // wave n-offset (A rows)
    const int wn   = (w & 3) * 64;      // wave m-offset (B rows)
    const int lrow = lane & 15;
    const int lhi  = lane >> 4;         // 0..3
    const int r7   = lrow & 7;

    const int id   = blockIdx.x;        // 0..255
    const int bn   = id & 15;
    const int slot = id >> 4;           // 0..15
    const int bn0  = bn << 8;

    // staging source (verified map): inst r covers rows r*64 + (tid>>3);
    // LDS slot q=tid&7 holds global chunk q ^ (row&7).
    const int arow  = tid >> 3;                      // 0..63
    const int aswz  = ((tid ^ arow) & 7) * 8;
    const int aoffb = (bn0 + arow) * 4096 + aswz;    // + R*262144 + k
    const int ldst  = w * 512;                       // wave chunk within inst region

    // read side (verified pattern): chunk (s*4+lhi) ^ (row&7), row&7 == lrow&7
    const int c0    = (lhi ^ r7) * 8;                // k-slice 0
    const int c1    = ((4 + lhi) ^ r7) * 8;          // k-slice 1
    const int baseA = (wm + lrow) * 64;
    const int baseB = 16384 + (wn + lrow) * 64;

    // segment table: slot<8: single seg-H(bm=slot, steps[32,64));
    // slot=8+p: seg-L(bm=p, [4p,32)) + whole(bm=15-p, [4(15-p),64))
    int nseg, bm_0, lo_0, hi_0, bm_1, lo_1, hi_1;
    if (slot < 8) {
        nseg = 1; bm_0 = slot;  lo_0 = 32;            hi_0 = 64;
        bm_1 = 0; lo_1 = 0; hi_1 = 0;
    } else {
        const int p = slot - 8;
        nseg = 2; bm_0 = p;      lo_0 = 4 * p;        hi_0 = 32;
                  bm_1 = 15 - p; lo_1 = 4 * (15 - p); hi_1 = 64;
    }

    floatx4 acc[8][4];
    bf16x8 af[8][2], bv[4][2];

#define STGA(D, R, T) __builtin_amdgcn_global_load_lds(                          \
    (const AS1 void*)(A + (size_t)(aoffb + (R) * 262144 + ((lo + (T)) << 6))),   \
    (AS3 void*)(lds + (D) * 32768 + (R) * 4096 + ldst), 16, 0, 0)
#define STGB(D, R, T) __builtin_amdgcn_global_load_lds(                          \
    (const AS1 void*)(Bt + (size_t)(boffb + (R) * 262144 + ((lo + (T)) << 6))),  \
    (AS3 void*)(lds + (D) * 32768 + 16384 + (R) * 4096 + ldst), 16, 0, 0)

#define RA(I, S, D) af[I][S] = *reinterpret_cast<const bf16x8*>(                 \
    lds + (D) * 32768 + baseA + (I) * 1024 + ((S) ? c1 : c0))
#define RB(J, S, D) bv[J][S] = *reinterpret_cast<const bf16x8*>(                 \
    lds + (D) * 32768 + baseB + (J) * 1024 + ((S) ? c1 : c0))

#define MQ(QI, QJ) do {                                                          \
    __builtin_amdgcn_s_setprio(1);                                               \
    _Pragma("unroll") for (int i_ = 0; i_ < 4; ++i_)                             \
    _Pragma("unroll") for (int j_ = 0; j_ < 2; ++j_)                             \
    _Pragma("unroll") for (int s_ = 0; s_ < 2; ++s_)                             \
        acc[(QI) * 4 + i_][(QJ) * 2 + j_] =                                      \
            __builtin_amdgcn_mfma_f32_16x16x32_bf16(                             \
                af[(QI) * 4 + i_][s_], bv[(QJ) * 2 + j_][s_],                    \
                acc[(QI) * 4 + i_][(QJ) * 2 + j_], 0, 0, 0);                     \
    __builtin_amdgcn_s_setprio(0);                                               \
} while (0)

    // one K-tile (4 phases, 8 barriers); tile T lives in buf T&1 == D
#define TILE(D, T) do {                                                          \
    /* P1: A-frags 0-3 + B-frags 0-1 */                                          \
    RA(0, 0, D); RA(0, 1, D); RA(1, 0, D); RA(1, 1, D);                          \
    RA(2, 0, D); RA(2, 1, D); RA(3, 0, D); RA(3, 1, D);                          \
    RB(0, 0, D); RB(0, 1, D); RB(1, 0, D); RB(1, 1, D);                          \
    if ((T) + 1 < Ls) { STGA((D) ^ 1, 1, (T) + 1); STGA((D) ^ 1, 3, (T) + 1); }  \
    bar(); LGKM0();                                                              \
    MQ(0, 0);                                                                    \
    bar();                                                                       \
    /* P2: B-frags 2-3 */                                                        \
    RB(2, 0, D); RB(2, 1, D); RB(3, 0, D); RB(3, 1, D);                          \
    if ((T) + 2 < Ls) { STGA(D, 0, (T) + 2); STGA(D, 2, (T) + 2); }              \
    bar(); LGKM0();                                                              \
    MQ(0, 1);                                                                    \
    bar();                                                                       \
    /* P3: A-frags 4-7 */                                                        \
    RA(4, 0, D); RA(4, 1, D); RA(5, 0, D); RA(5, 1, D);                          \
    RA(6, 0, D); RA(6, 1, D); RA(7, 0, D); RA(7, 1, D);                          \
    if ((T) + 2 < Ls) { STGB(D, 0, (T) + 2); STGB(D, 1, (T) + 2); }              \
    bar(); LGKM0();                                                              \
    MQ(1, 0);                                                                    \
    bar();                                                                       \
    /* P4: no reads */                                                           \
    if ((T) + 2 < Ls) { STGB(D, 2, (T) + 2); STGB(D, 3, (T) + 2); }              \
    bar();                                                                       \
    MQ(1, 1);                                                                    \
    if ((T) + 2 < Ls)      { VMCNT6(); }                                         \
    else if ((T) + 1 < Ls) { VMCNT0(); }                                         \
    bar();                                                                       \
} while (0)

    for (int sg = 0; sg < nseg; ++sg) {
        int bm, lo, hi;
        if (sg == 0) { bm = bm_0; lo = lo_0; hi = hi_0; }
        else         { bm = bm_1; lo = lo_1; hi = hi_1; }
        const int Ls  = hi - lo;        // K-tiles this segment (even, >= 4)
        const int bm0 = bm << 8;
        const int boffb = (bm0 + arow) * 4096 + aswz;

#pragma unroll
        for (int i = 0; i < 8; ++i)
#pragma unroll
            for (int j = 0; j < 4; ++j)
                acc[i][j] = (floatx4)0.0f;

        // ---- prologue: tile0 complete (8) + tile1 partial (6); vmcnt(6)
        //      confirms exactly tile 0. ----
        STGA(0, 0, 0); STGA(0, 2, 0);
        STGB(0, 0, 0); STGB(0, 1, 0); STGB(0, 2, 0); STGB(0, 3, 0);
        STGA(0, 1, 0); STGA(0, 3, 0);
        STGA(1, 0, 1); STGA(1, 2, 1);
        STGB(1, 0, 1); STGB(1, 1, 1); STGB(1, 2, 1); STGB(1, 3, 1);
        VMCNT6();
        bar();

        // ---- main loop: Ls is always even; tile T in buf T&1 ----
        for (int T = 0; T + 1 < Ls; T += 2) {
            TILE(0, T);
            TILE(1, T + 1);
        }

        // ---- epilogue: C/D layout col=lane&15 (m), row=(lane>>4)*4+reg [m89] ----
        if (bm < 8) {
            // split tile: zero-initialized region, HW fp32 atomic add
#pragma unroll
            for (int i = 0; i < 8; ++i) {
                const int rown = bn0 + wm + i * 16 + lhi * 4;
#pragma unroll
                for (int j = 0; j < 4; ++j) {
                    const int colm = bm0 + wn + j * 16 + lrow;
                    float* cp = C + (size_t)rown * 4096 + colm;
#pragma unroll
                    for (int rr = 0; rr < 4; ++rr)
                        unsafeAtomicAdd(cp + (size_t)rr * 4096, acc[i][j][rr]);
                }
            }
        } else {
#pragma unroll
            for (int i = 0; i < 8; ++i) {
                const int rown = bn0 + wm + i * 16 + lhi * 4;
#pragma unroll
                for (int j = 0; j < 4; ++j) {
                    const int colm = bm0 + wn + j * 16 + lrow;
                    float* cp = C + (size_t)rown * 4096 + colm;
#pragma unroll
                    for (int rr = 0; rr < 4; ++rr)
                        cp[(size_t)rr * 4096] = acc[i][j][rr];
                }
            }
        }
        // loop ends with TILE's trailing bar -> LDS safe for next segment's staging
    }
}

extern "C" void kernel_launch(void* const* d_in, const int* in_sizes, int n_in,
                              void* d_out, int out_size, void* d_ws, size_t ws_size,
                              hipStream_t stream)
{
    const float* x    = (const float*)d_in[0];   // [4096,8]
    const float* grid = (const float*)d_in[1];   // [4096,8]
    const float* ci   = (const float*)d_in[2];   // [4096,4096]
    const float* ls   = (const float*)d_in[3];   // [8]
    float* out = (float*)d_out;                  // [4096,4096] fp32

    u16* wsA  = (u16*)d_ws;                            // k_star bf16, 33.5 MB
    u16* wsBt = (u16*)d_ws + (size_t)MGRD * MGRD;      // chol_inv^T bf16, 33.5 MB

    prep_kernel<<<dim3(512 + 4096 + 1024), 256, 0, stream>>>(x, grid, ls, ci, wsA, wsBt, out);
    gemm_8ph_kernel<<<dim3(256), 512, 0, stream>>>(wsA, wsBt, out);
}